// Round 3
// baseline (31.990 us; speedup 1.0000x reference)
//
#include <hip/hip_runtime.h>
#include <math.h>

#define H 4096
#define NSTEPS 1000
#define NT 512
#define JPT 8    // H / NT contiguous hidden units per thread
// ws layout (float4 rows of 512): rows 0-9 wi, 10-19 wg, 20-29 wo,
// 30-35 folded biases (bI,bG,bO x2), 36-49 wl (7 logits x2). 50 rows total.
#define WS_ROWS 50

// ---- Kernel 1: parallel repack of live weights into thread-interleaved ws ----
// 50 blocks x 512 threads; block q produces ws row q. Spreads the HBM cold read
// over 50 CUs and leaves the packed bytes resident in the Infinity Cache.
__global__ __launch_bounds__(NT, 1) void repack_kernel(
    const float* __restrict__ W_ih,
    const float* __restrict__ b_ih,
    const float* __restrict__ b_hh,
    const float* __restrict__ W_lin,
    float4* __restrict__ ws4)
{
    const int q = blockIdx.x;      // 0..49
    const int t = threadIdx.x;     // 0..511
    float4 v;
    if (q < 30) {
        // W_ih gate rows: live gates i (off 0), g (off 2H), o (off 3H); 5 f32/row.
        const int gate = q / 10;
        const int qq   = q % 10;
        const size_t goff = (gate == 0) ? 0 : (gate == 1 ? (size_t)2 * H * 5 : (size_t)3 * H * 5);
        const float4* src = (const float4*)(W_ih + goff);
        v = src[(size_t)t * 10 + qq];           // thread t's 40-float slice, float4 #qq
    } else if (q < 36) {
        const int gq = q - 30, gate = gq >> 1, qq = gq & 1;
        const size_t boff = (gate == 0) ? 0 : (gate == 1 ? (size_t)2 * H : (size_t)3 * H);
        const float4* s0 = (const float4*)(b_ih + boff);
        const float4* s1 = (const float4*)(b_hh + boff);
        float4 a = s0[(size_t)t * 2 + qq], b = s1[(size_t)t * 2 + qq];
        v = make_float4(a.x + b.x, a.y + b.y, a.z + b.z, a.w + b.w);   // fold b_ih+b_hh
    } else {
        const int lq = q - 36, l = lq >> 1, qq = lq & 1;
        const float4* src = (const float4*)(W_lin + (size_t)l * H);
        v = src[(size_t)t * 2 + qq];
    }
    ws4[(size_t)q * NT + t] = v;   // coalesced 8KB row per block
}

// ---- Kernel 2: the autoregressive solver (single block) ----
__global__ __launch_bounds__(NT, 1) void sketch_kernel(
    const float4* __restrict__ ws4,
    const float* __restrict__ b_lin,
    const float* __restrict__ noise,
    float* __restrict__ out)
{
    const int tid  = threadIdx.x;
    const int lane = tid & 63;
    const int wave = tid >> 6;                 // 8 waves

    __shared__ __align__(16) float s_noise[NSTEPS * 2];
    __shared__ float s_part[8][8];             // [wave][logit]
    __shared__ float s_prev[8];

    if (tid < NSTEPS * 2 / 4)
        ((float4*)s_noise)[tid] = ((const float4*)noise)[tid];

    // ---- register-resident weights: 50 coalesced float4 loads, L3-warm ----
    float wi[40], wg[40], wo[40];
    float bI[JPT], bG[JPT], bO[JPT];
    float wl[7][JPT];
#pragma unroll
    for (int q = 0; q < 10; ++q) {
        float4 vi = ws4[(size_t)(q     ) * NT + tid];
        float4 vg = ws4[(size_t)(q + 10) * NT + tid];
        float4 vo = ws4[(size_t)(q + 20) * NT + tid];
        wi[4*q+0] = vi.x; wi[4*q+1] = vi.y; wi[4*q+2] = vi.z; wi[4*q+3] = vi.w;
        wg[4*q+0] = vg.x; wg[4*q+1] = vg.y; wg[4*q+2] = vg.z; wg[4*q+3] = vg.w;
        wo[4*q+0] = vo.x; wo[4*q+1] = vo.y; wo[4*q+2] = vo.z; wo[4*q+3] = vo.w;
    }
#pragma unroll
    for (int qq = 0; qq < 2; ++qq) {
        float4 a = ws4[(size_t)(30 + qq) * NT + tid];
        float4 g = ws4[(size_t)(32 + qq) * NT + tid];
        float4 o = ws4[(size_t)(34 + qq) * NT + tid];
        bI[4*qq+0] = a.x; bI[4*qq+1] = a.y; bI[4*qq+2] = a.z; bI[4*qq+3] = a.w;
        bG[4*qq+0] = g.x; bG[4*qq+1] = g.y; bG[4*qq+2] = g.z; bG[4*qq+3] = g.w;
        bO[4*qq+0] = o.x; bO[4*qq+1] = o.y; bO[4*qq+2] = o.z; bO[4*qq+3] = o.w;
    }
#pragma unroll
    for (int l = 0; l < 7; ++l) {
#pragma unroll
        for (int qq = 0; qq < 2; ++qq) {
            float4 v = ws4[(size_t)(36 + l * 2 + qq) * NT + tid];
            wl[l][4*qq+0] = v.x; wl[l][4*qq+1] = v.y; wl[l][4*qq+2] = v.z; wl[l][4*qq+3] = v.w;
        }
    }
    const float blin = (lane < 7 && wave == 0) ? b_lin[lane] : 0.f;

    if (tid == 0) {
        out[0] = 0.f; out[1] = 0.f; out[2] = 1.f; out[3] = 0.f; out[4] = 0.f;
    }
    __syncthreads();

    float pv0 = 0.f, pv1 = 0.f, pv2 = 1.f, pv3 = 0.f, pv4 = 0.f;

    int t;
    for (t = 0; t < NSTEPS; ++t) {
        float a0 = 0.f, a1 = 0.f, a2 = 0.f, a3 = 0.f, a4 = 0.f, a5 = 0.f, a6 = 0.f;
#pragma unroll
        for (int r = 0; r < JPT; ++r) {
            float gi = fmaf(wi[r*5+4], pv4, fmaf(wi[r*5+3], pv3, fmaf(wi[r*5+2], pv2, fmaf(wi[r*5+1], pv1, fmaf(wi[r*5+0], pv0, bI[r])))));
            float gg = fmaf(wg[r*5+4], pv4, fmaf(wg[r*5+3], pv3, fmaf(wg[r*5+2], pv2, fmaf(wg[r*5+1], pv1, fmaf(wg[r*5+0], pv0, bG[r])))));
            float go = fmaf(wo[r*5+4], pv4, fmaf(wo[r*5+3], pv3, fmaf(wo[r*5+2], pv2, fmaf(wo[r*5+1], pv1, fmaf(wo[r*5+0], pv0, bO[r])))));
            float ei = __expf(-gi);
            float eg = __expf(gg + gg);
            float cg = __fdividef(eg - 1.f, (1.f + ei) * (eg + 1.f));   // sig(i)*tanh(g)
            float eo = __expf(-go);
            float ec = __expf(cg + cg);
            float hj = __fdividef(ec - 1.f, (1.f + eo) * (ec + 1.f));   // sig(o)*tanh(c)
            a0 = fmaf(wl[0][r], hj, a0);
            a1 = fmaf(wl[1][r], hj, a1);
            a2 = fmaf(wl[2][r], hj, a2);
            a3 = fmaf(wl[3][r], hj, a3);
            a4 = fmaf(wl[4][r], hj, a4);
            a5 = fmaf(wl[5][r], hj, a5);
            a6 = fmaf(wl[6][r], hj, a6);
        }
#pragma unroll
        for (int m = 1; m < 64; m <<= 1) {
            a0 += __shfl_xor(a0, m, 64);
            a1 += __shfl_xor(a1, m, 64);
            a2 += __shfl_xor(a2, m, 64);
            a3 += __shfl_xor(a3, m, 64);
            a4 += __shfl_xor(a4, m, 64);
            a5 += __shfl_xor(a5, m, 64);
            a6 += __shfl_xor(a6, m, 64);
        }
        if (lane == 0) {
            s_part[wave][0] = a0; s_part[wave][1] = a1; s_part[wave][2] = a2;
            s_part[wave][3] = a3; s_part[wave][4] = a4; s_part[wave][5] = a5;
            s_part[wave][6] = a6;
        }
        __syncthreads();
        if (wave == 0) {
            // lanes 0..6 each finish one logit (cross-wave sum + tanh via HW exp)
            const int l = lane < 7 ? lane : 0;
            float s = blin;
#pragma unroll
            for (int w = 0; w < 8; ++w) s += s_part[w][l];
            float e2 = __expf(s + s);
            float lg = __fdividef(e2 - 1.f, e2 + 1.f);
            float l0 = __shfl(lg, 0, 64), l1 = __shfl(lg, 1, 64), l2 = __shfl(lg, 2, 64);
            float l3 = __shfl(lg, 3, 64), l4 = __shfl(lg, 4, 64), l5 = __shfl(lg, 5, 64);
            float l6 = __shfl(lg, 6, 64);
            if (lane == 0) {
                float mx = fmaxf(l4, fmaxf(l5, l6));
                float e0 = __expf(l4 - mx), e1 = __expf(l5 - mx), e2b = __expf(l6 - mx);
                float inv = __fdividef(1.f, e0 + e1 + e2b);
                float p0 = e0 * inv, p1 = e1 * inv, p2 = e2b * inv;
                float x0 = l0 + __expf(l1 * 0.5f) * s_noise[2 * t];
                float x1 = l2 + __expf(l3 * 0.5f) * s_noise[2 * t + 1];
                float* row = out + (t + 1) * 5;
                row[0] = x0; row[1] = x1; row[2] = p0; row[3] = p1; row[4] = p2;
                s_prev[0] = x0; s_prev[1] = x1; s_prev[2] = p0; s_prev[3] = p1; s_prev[4] = p2;
                // argmax(new_row[2:]) == 2 (numpy first-index ties) iff p2 strictly beats p0 and p1
                s_prev[5] = (p2 > p0 && p2 > p1) ? 1.f : 0.f;
            }
        }
        __syncthreads();
        pv0 = s_prev[0]; pv1 = s_prev[1]; pv2 = s_prev[2]; pv3 = s_prev[3]; pv4 = s_prev[4];
        if (s_prev[5] != 0.f) break;   // uniform across block
    }

    // zero rows after the stop step (t==NSTEPS -> start past end, no-op)
    const int start = (t + 2) * 5;
    for (int i = start + tid; i < (NSTEPS + 1) * 5; i += NT) out[i] = 0.f;
}

extern "C" void kernel_launch(void* const* d_in, const int* in_sizes, int n_in,
                              void* d_out, int out_size, void* d_ws, size_t ws_size,
                              hipStream_t stream) {
    const float* W_ih  = (const float*)d_in[0];
    // d_in[1] = W_hh: mathematically dead (h = c = 0 every step) — never read.
    const float* b_ih  = (const float*)d_in[2];
    const float* b_hh  = (const float*)d_in[3];
    const float* W_lin = (const float*)d_in[4];
    const float* b_lin = (const float*)d_in[5];
    const float* noise = (const float*)d_in[6];
    float* out = (float*)d_out;
    float4* ws4 = (float4*)d_ws;   // 50*512 float4 = 400KB << ws_size

    hipLaunchKernelGGL(repack_kernel, dim3(WS_ROWS), dim3(NT), 0, stream,
                       W_ih, b_ih, b_hh, W_lin, ws4);
    hipLaunchKernelGGL(sketch_kernel, dim3(1), dim3(NT), 0, stream,
                       ws4, b_lin, noise, out);
}

// Round 5
// 28.518 us; speedup vs baseline: 1.1217x; 1.1217x over previous
//
#include <hip/hip_runtime.h>
#include <math.h>

#define H 4096
#define NSTEPS 1000
#define NT 512
#define JPT 8            // H / NT contiguous hidden units per solver thread
#define NPACK 25         // packed uint4 rows (each = two f32 rows of round-3 layout)
#define MAGIC 0x5A17C0DEu

// ws layout: bytes [0, 200KB): packed bf16 weights as uint4[NPACK][NT]
//            bytes [512KB, ...): 25 completion flags (uint each)

__device__ __forceinline__ unsigned short f2bf(float f) {
    unsigned u = __builtin_bit_cast(unsigned, f);
    u += 0x7FFFu + ((u >> 16) & 1u);          // round-to-nearest-even
    return (unsigned short)(u >> 16);
}
__device__ __forceinline__ float bf2f(unsigned h) {
    unsigned u = h << 16;
    return __builtin_bit_cast(float, u);
}

// f32 "row" q (0..49), thread t: same verified mapping as round 3.
__device__ __forceinline__ float4 load_f32row(int q, int t,
    const float* W_ih, const float* b_ih, const float* b_hh, const float* W_lin)
{
    if (q < 30) {                              // gate weight rows (i,g,o)
        const int gate = q / 10, qq = q % 10;
        const size_t goff = (gate == 0) ? 0 : (gate == 1 ? (size_t)2 * H * 5 : (size_t)3 * H * 5);
        return ((const float4*)(W_ih + goff))[(size_t)t * 10 + qq];
    } else if (q < 36) {                       // folded biases
        const int gq = q - 30, gate = gq >> 1, qq = gq & 1;
        const size_t boff = (gate == 0) ? 0 : (gate == 1 ? (size_t)2 * H : (size_t)3 * H);
        float4 a = ((const float4*)(b_ih + boff))[(size_t)t * 2 + qq];
        float4 b = ((const float4*)(b_hh + boff))[(size_t)t * 2 + qq];
        return make_float4(a.x + b.x, a.y + b.y, a.z + b.z, a.w + b.w);
    } else {                                   // W_lin rows
        const int lq = q - 36, l = lq >> 1, qq = lq & 1;
        return ((const float4*)(W_lin + (size_t)l * H))[(size_t)t * 2 + qq];
    }
}

__global__ __launch_bounds__(NT, 1) void sketch_fused(
    const float* __restrict__ W_ih,
    const float* __restrict__ b_ih,
    const float* __restrict__ b_hh,
    const float* __restrict__ W_lin,
    const float* __restrict__ b_lin,
    const float* __restrict__ noise,
    float* __restrict__ out,
    unsigned char* __restrict__ ws)
{
    uint4* ws4 = (uint4*)ws;
    unsigned* flags = (unsigned*)(ws + (512u << 10));
    const int tid = threadIdx.x;

    if (blockIdx.x < NPACK) {
        // ---------------- repacker: one packed row per block ----------------
        const int qp = blockIdx.x;
        float4 A = load_f32row(2 * qp,     tid, W_ih, b_ih, b_hh, W_lin);
        float4 B = load_f32row(2 * qp + 1, tid, W_ih, b_ih, b_hh, W_lin);
        uint4 v;
        v.x = (unsigned)f2bf(A.x) | ((unsigned)f2bf(A.y) << 16);
        v.y = (unsigned)f2bf(A.z) | ((unsigned)f2bf(A.w) << 16);
        v.z = (unsigned)f2bf(B.x) | ((unsigned)f2bf(B.y) << 16);
        v.w = (unsigned)f2bf(B.z) | ((unsigned)f2bf(B.w) << 16);
        ws4[(size_t)qp * NT + tid] = v;       // coalesced 8KB row per block
        __threadfence();                      // agent release: wb so solver's XCD can see it
        __syncthreads();
        if (tid == 0)
            __hip_atomic_store(&flags[qp], MAGIC, __ATOMIC_RELEASE, __HIP_MEMORY_SCOPE_AGENT);
        return;
    }

    // ---------------- solver block ----------------
    const int lane = tid & 63;
    const int wave = tid >> 6;                 // 8 waves

    __shared__ __align__(16) float s_noise[NSTEPS * 2];
    __shared__ float s_part[8][8];
    __shared__ float s_prev[8];

    if (tid < NSTEPS * 2 / 4)
        ((float4*)s_noise)[tid] = ((const float4*)noise)[tid];

    // Pre-write row 0 and zeros for ALL rows (overlaps the repack wait);
    // the step loop overwrites rows 1..T+1 afterwards.
    for (int i = tid; i < (NSTEPS + 1) * 5; i += NT) out[i] = (i == 2) ? 1.f : 0.f;

    // wait for all repackers (device-scope flags); lanes 0..24 of wave 0 poll
    if (wave == 0 && lane < NPACK) {
        int guard = 0;
        while (__hip_atomic_load(&flags[lane], __ATOMIC_RELAXED, __HIP_MEMORY_SCOPE_AGENT) != MAGIC) {
            __builtin_amdgcn_s_sleep(2);
            if (++guard > (1 << 26)) break;    // safety: never hard-hang the queue
        }
    }
    __syncthreads();
    __threadfence();                           // agent acquire: invalidate stale L1/L2

    // ---- register-resident weights from packed bf16 ws (200KB, coalesced) ----
    float wi[40], wg[40], wo[40];
    float bI[JPT], bG[JPT], bO[JPT];
    float wl[7][JPT];
#pragma unroll
    for (int qp = 0; qp < NPACK; ++qp) {
        uint4 v = ws4[(size_t)qp * NT + tid];
        float f0 = bf2f(v.x & 0xFFFFu), f1 = bf2f(v.x >> 16);
        float f2 = bf2f(v.y & 0xFFFFu), f3 = bf2f(v.y >> 16);
        float f4 = bf2f(v.z & 0xFFFFu), f5 = bf2f(v.z >> 16);
        float f6 = bf2f(v.w & 0xFFFFu), f7 = bf2f(v.w >> 16);
        if (qp < 5) {
            wi[8*qp+0]=f0; wi[8*qp+1]=f1; wi[8*qp+2]=f2; wi[8*qp+3]=f3;
            wi[8*qp+4]=f4; wi[8*qp+5]=f5; wi[8*qp+6]=f6; wi[8*qp+7]=f7;
        } else if (qp < 10) {
            const int b = qp - 5;
            wg[8*b+0]=f0; wg[8*b+1]=f1; wg[8*b+2]=f2; wg[8*b+3]=f3;
            wg[8*b+4]=f4; wg[8*b+5]=f5; wg[8*b+6]=f6; wg[8*b+7]=f7;
        } else if (qp < 15) {
            const int b = qp - 10;
            wo[8*b+0]=f0; wo[8*b+1]=f1; wo[8*b+2]=f2; wo[8*b+3]=f3;
            wo[8*b+4]=f4; wo[8*b+5]=f5; wo[8*b+6]=f6; wo[8*b+7]=f7;
        } else if (qp == 15) {
            bI[0]=f0; bI[1]=f1; bI[2]=f2; bI[3]=f3; bI[4]=f4; bI[5]=f5; bI[6]=f6; bI[7]=f7;
        } else if (qp == 16) {
            bG[0]=f0; bG[1]=f1; bG[2]=f2; bG[3]=f3; bG[4]=f4; bG[5]=f5; bG[6]=f6; bG[7]=f7;
        } else if (qp == 17) {
            bO[0]=f0; bO[1]=f1; bO[2]=f2; bO[3]=f3; bO[4]=f4; bO[5]=f5; bO[6]=f6; bO[7]=f7;
        } else {
            const int l = qp - 18;
            wl[l][0]=f0; wl[l][1]=f1; wl[l][2]=f2; wl[l][3]=f3;
            wl[l][4]=f4; wl[l][5]=f5; wl[l][6]=f6; wl[l][7]=f7;
        }
    }
    const float blin = (lane < 7 && wave == 0) ? b_lin[lane] : 0.f;

    float pv0 = 0.f, pv1 = 0.f, pv2 = 1.f, pv3 = 0.f, pv4 = 0.f;

    for (int t = 0; t < NSTEPS; ++t) {
        float a0 = 0.f, a1 = 0.f, a2 = 0.f, a3 = 0.f, a4 = 0.f, a5 = 0.f, a6 = 0.f;
#pragma unroll
        for (int r = 0; r < JPT; ++r) {
            float gi = fmaf(wi[r*5+4], pv4, fmaf(wi[r*5+3], pv3, fmaf(wi[r*5+2], pv2, fmaf(wi[r*5+1], pv1, fmaf(wi[r*5+0], pv0, bI[r])))));
            float gg = fmaf(wg[r*5+4], pv4, fmaf(wg[r*5+3], pv3, fmaf(wg[r*5+2], pv2, fmaf(wg[r*5+1], pv1, fmaf(wg[r*5+0], pv0, bG[r])))));
            float go = fmaf(wo[r*5+4], pv4, fmaf(wo[r*5+3], pv3, fmaf(wo[r*5+2], pv2, fmaf(wo[r*5+1], pv1, fmaf(wo[r*5+0], pv0, bO[r])))));
            float ei = __expf(-gi);
            float eg = __expf(gg + gg);
            float cg = __fdividef(eg - 1.f, (1.f + ei) * (eg + 1.f));   // sig(i)*tanh(g)
            float eo = __expf(-go);
            float ec = __expf(cg + cg);
            float hj = __fdividef(ec - 1.f, (1.f + eo) * (ec + 1.f));   // sig(o)*tanh(c)
            a0 = fmaf(wl[0][r], hj, a0);
            a1 = fmaf(wl[1][r], hj, a1);
            a2 = fmaf(wl[2][r], hj, a2);
            a3 = fmaf(wl[3][r], hj, a3);
            a4 = fmaf(wl[4][r], hj, a4);
            a5 = fmaf(wl[5][r], hj, a5);
            a6 = fmaf(wl[6][r], hj, a6);
        }
#pragma unroll
        for (int m = 1; m < 64; m <<= 1) {
            a0 += __shfl_xor(a0, m, 64);
            a1 += __shfl_xor(a1, m, 64);
            a2 += __shfl_xor(a2, m, 64);
            a3 += __shfl_xor(a3, m, 64);
            a4 += __shfl_xor(a4, m, 64);
            a5 += __shfl_xor(a5, m, 64);
            a6 += __shfl_xor(a6, m, 64);
        }
        if (lane == 0) {
            s_part[wave][0] = a0; s_part[wave][1] = a1; s_part[wave][2] = a2;
            s_part[wave][3] = a3; s_part[wave][4] = a4; s_part[wave][5] = a5;
            s_part[wave][6] = a6;
        }
        __syncthreads();
        if (wave == 0) {
            const int l = lane < 7 ? lane : 0;
            float s = blin;
#pragma unroll
            for (int w = 0; w < 8; ++w) s += s_part[w][l];
            float e2 = __expf(s + s);
            float lg = __fdividef(e2 - 1.f, e2 + 1.f);
            float l0 = __shfl(lg, 0, 64), l1 = __shfl(lg, 1, 64), l2 = __shfl(lg, 2, 64);
            float l3 = __shfl(lg, 3, 64), l4 = __shfl(lg, 4, 64), l5 = __shfl(lg, 5, 64);
            float l6 = __shfl(lg, 6, 64);
            if (lane == 0) {
                float mx = fmaxf(l4, fmaxf(l5, l6));
                float e0 = __expf(l4 - mx), e1 = __expf(l5 - mx), e2b = __expf(l6 - mx);
                float inv = __fdividef(1.f, e0 + e1 + e2b);
                float p0 = e0 * inv, p1 = e1 * inv, p2 = e2b * inv;
                float x0 = l0 + __expf(l1 * 0.5f) * s_noise[2 * t];
                float x1 = l2 + __expf(l3 * 0.5f) * s_noise[2 * t + 1];
                float* row = out + (t + 1) * 5;
                row[0] = x0; row[1] = x1; row[2] = p0; row[3] = p1; row[4] = p2;
                s_prev[0] = x0; s_prev[1] = x1; s_prev[2] = p0; s_prev[3] = p1; s_prev[4] = p2;
                // argmax(new_row[2:]) == 2 (numpy first-index ties) iff p2 strictly beats p0 and p1
                s_prev[5] = (p2 > p0 && p2 > p1) ? 1.f : 0.f;
            }
        }
        __syncthreads();
        pv0 = s_prev[0]; pv1 = s_prev[1]; pv2 = s_prev[2]; pv3 = s_prev[3]; pv4 = s_prev[4];
        if (s_prev[5] != 0.f) break;   // uniform across block; later rows pre-zeroed
    }
}

extern "C" void kernel_launch(void* const* d_in, const int* in_sizes, int n_in,
                              void* d_out, int out_size, void* d_ws, size_t ws_size,
                              hipStream_t stream) {
    const float* W_ih  = (const float*)d_in[0];
    // d_in[1] = W_hh: mathematically dead (h = c = 0 every step) — never read.
    const float* b_ih  = (const float*)d_in[2];
    const float* b_hh  = (const float*)d_in[3];
    const float* W_lin = (const float*)d_in[4];
    const float* b_lin = (const float*)d_in[5];
    const float* noise = (const float*)d_in[6];
    float* out = (float*)d_out;

    hipLaunchKernelGGL(sketch_fused, dim3(NPACK + 1), dim3(NT), 0, stream,
                       W_ih, b_ih, b_hh, W_lin, b_lin, noise, out,
                       (unsigned char*)d_ws);
}

// Round 6
// 26.179 us; speedup vs baseline: 1.2219x; 1.0894x over previous
//
#include <hip/hip_runtime.h>
#include <math.h>

#define H 4096
#define NSTEPS 1000
#define NT 512
#define JPT 8            // H / NT contiguous hidden units per solver thread
#define NPACK 25         // packed uint4 rows (each = two f32 rows of round-3 layout)
#define MAGIC 0x5A17C0DEull

// ws layout: bytes [0, 200KB): packed bf16 weights as u64 pairs [NPACK][NT][2]
//            bytes [512KB, ...): 25 completion flags (u64 each)
// ALL ws traffic uses relaxed AGENT-scope atomics (sc1): stores write through the
// non-coherent per-XCD L2 to the coherent point; loads bypass the (stale, fill-
// poisoned) local L2. No __threadfence -> no buffer_wbl2 dirty-L2 drain stalls.

__device__ __forceinline__ unsigned short f2bf(float f) {
    unsigned u = __builtin_bit_cast(unsigned, f);
    u += 0x7FFFu + ((u >> 16) & 1u);          // round-to-nearest-even
    return (unsigned short)(u >> 16);
}
__device__ __forceinline__ float bf2f(unsigned h) {
    unsigned u = h << 16;
    return __builtin_bit_cast(float, u);
}

// f32 "row" q (0..49), thread t: same verified mapping as rounds 3-5.
__device__ __forceinline__ float4 load_f32row(int q, int t,
    const float* W_ih, const float* b_ih, const float* b_hh, const float* W_lin)
{
    if (q < 30) {                              // gate weight rows (i,g,o)
        const int gate = q / 10, qq = q % 10;
        const size_t goff = (gate == 0) ? 0 : (gate == 1 ? (size_t)2 * H * 5 : (size_t)3 * H * 5);
        return ((const float4*)(W_ih + goff))[(size_t)t * 10 + qq];
    } else if (q < 36) {                       // folded biases
        const int gq = q - 30, gate = gq >> 1, qq = gq & 1;
        const size_t boff = (gate == 0) ? 0 : (gate == 1 ? (size_t)2 * H : (size_t)3 * H);
        float4 a = ((const float4*)(b_ih + boff))[(size_t)t * 2 + qq];
        float4 b = ((const float4*)(b_hh + boff))[(size_t)t * 2 + qq];
        return make_float4(a.x + b.x, a.y + b.y, a.z + b.z, a.w + b.w);
    } else {                                   // W_lin rows
        const int lq = q - 36, l = lq >> 1, qq = lq & 1;
        return ((const float4*)(W_lin + (size_t)l * H))[(size_t)t * 2 + qq];
    }
}

__global__ __launch_bounds__(NT, 1) void sketch_fused(
    const float* __restrict__ W_ih,
    const float* __restrict__ b_ih,
    const float* __restrict__ b_hh,
    const float* __restrict__ W_lin,
    const float* __restrict__ b_lin,
    const float* __restrict__ noise,
    float* __restrict__ out,
    unsigned char* __restrict__ ws)
{
    unsigned long long* ws8 = (unsigned long long*)ws;
    unsigned long long* flags = (unsigned long long*)(ws + (512u << 10));
    const int tid = threadIdx.x;

    if (blockIdx.x < NPACK) {
        // ---------------- repacker: one packed row per block ----------------
        const int qp = blockIdx.x;
        float4 A = load_f32row(2 * qp,     tid, W_ih, b_ih, b_hh, W_lin);
        float4 B = load_f32row(2 * qp + 1, tid, W_ih, b_ih, b_hh, W_lin);
        unsigned x0 = (unsigned)f2bf(A.x) | ((unsigned)f2bf(A.y) << 16);
        unsigned x1 = (unsigned)f2bf(A.z) | ((unsigned)f2bf(A.w) << 16);
        unsigned x2 = (unsigned)f2bf(B.x) | ((unsigned)f2bf(B.y) << 16);
        unsigned x3 = (unsigned)f2bf(B.z) | ((unsigned)f2bf(B.w) << 16);
        unsigned long long lo = (unsigned long long)x0 | ((unsigned long long)x1 << 32);
        unsigned long long hi = (unsigned long long)x2 | ((unsigned long long)x3 << 32);
        const size_t base = ((size_t)qp * NT + tid) * 2;
        __hip_atomic_store(&ws8[base],     lo, __ATOMIC_RELAXED, __HIP_MEMORY_SCOPE_AGENT);
        __hip_atomic_store(&ws8[base + 1], hi, __ATOMIC_RELAXED, __HIP_MEMORY_SCOPE_AGENT);
        asm volatile("s_waitcnt vmcnt(0)" ::: "memory");   // per-wave: stores at coherent point
        __syncthreads();                                    // all waves done
        if (tid == 0)
            __hip_atomic_store(&flags[qp], MAGIC, __ATOMIC_RELAXED, __HIP_MEMORY_SCOPE_AGENT);
        return;
    }

    // ---------------- solver block ----------------
    const int lane = tid & 63;
    const int wave = tid >> 6;                 // 8 waves

    __shared__ __align__(16) float s_noise[NSTEPS * 2];
    __shared__ float s_part[8][8];
    __shared__ float s_prev[8];

    if (tid < NSTEPS * 2 / 4)
        ((float4*)s_noise)[tid] = ((const float4*)noise)[tid];

    // Pre-write row 0 and zeros for ALL rows (overlaps the repack wait);
    // the step loop overwrites rows 1..T+1 afterwards.
    for (int i = tid; i < (NSTEPS + 1) * 5; i += NT) out[i] = (i == 2) ? 1.f : 0.f;

    // wait for all repackers; lanes 0..24 of wave 0 poll (sc1 loads, no fence needed)
    if (wave == 0 && lane < NPACK) {
        int guard = 0;
        while (__hip_atomic_load(&flags[lane], __ATOMIC_RELAXED, __HIP_MEMORY_SCOPE_AGENT) != MAGIC) {
            __builtin_amdgcn_s_sleep(2);
            if (++guard > (1 << 26)) break;    // safety: never hard-hang the queue
        }
    }
    __syncthreads();

    // ---- register-resident weights from packed bf16 ws (200KB, sc1 loads) ----
    float wi[40], wg[40], wo[40];
    float bI[JPT], bG[JPT], bO[JPT];
    float wl[7][JPT];

    // batched: 13 rows, unpack, 12 rows, unpack (caps VGPR peak < 256)
    unsigned long long rawA[26], rawB[24];
#pragma unroll
    for (int qp = 0; qp < 13; ++qp) {
        const size_t base = ((size_t)qp * NT + tid) * 2;
        rawA[2*qp]   = __hip_atomic_load(&ws8[base],     __ATOMIC_RELAXED, __HIP_MEMORY_SCOPE_AGENT);
        rawA[2*qp+1] = __hip_atomic_load(&ws8[base + 1], __ATOMIC_RELAXED, __HIP_MEMORY_SCOPE_AGENT);
    }
#pragma unroll
    for (int qp = 13; qp < NPACK; ++qp) {
        const size_t base = ((size_t)qp * NT + tid) * 2;
        rawB[2*(qp-13)]   = __hip_atomic_load(&ws8[base],     __ATOMIC_RELAXED, __HIP_MEMORY_SCOPE_AGENT);
        rawB[2*(qp-13)+1] = __hip_atomic_load(&ws8[base + 1], __ATOMIC_RELAXED, __HIP_MEMORY_SCOPE_AGENT);
    }

#pragma unroll
    for (int qp = 0; qp < NPACK; ++qp) {
        unsigned long long lo = (qp < 13) ? rawA[2*qp]   : rawB[2*(qp-13)];
        unsigned long long hi = (qp < 13) ? rawA[2*qp+1] : rawB[2*(qp-13)+1];
        unsigned vx = (unsigned)lo, vy = (unsigned)(lo >> 32);
        unsigned vz = (unsigned)hi, vw = (unsigned)(hi >> 32);
        float f0 = bf2f(vx & 0xFFFFu), f1 = bf2f(vx >> 16);
        float f2 = bf2f(vy & 0xFFFFu), f3 = bf2f(vy >> 16);
        float f4 = bf2f(vz & 0xFFFFu), f5 = bf2f(vz >> 16);
        float f6 = bf2f(vw & 0xFFFFu), f7 = bf2f(vw >> 16);
        if (qp < 5) {
            wi[8*qp+0]=f0; wi[8*qp+1]=f1; wi[8*qp+2]=f2; wi[8*qp+3]=f3;
            wi[8*qp+4]=f4; wi[8*qp+5]=f5; wi[8*qp+6]=f6; wi[8*qp+7]=f7;
        } else if (qp < 10) {
            const int b = qp - 5;
            wg[8*b+0]=f0; wg[8*b+1]=f1; wg[8*b+2]=f2; wg[8*b+3]=f3;
            wg[8*b+4]=f4; wg[8*b+5]=f5; wg[8*b+6]=f6; wg[8*b+7]=f7;
        } else if (qp < 15) {
            const int b = qp - 10;
            wo[8*b+0]=f0; wo[8*b+1]=f1; wo[8*b+2]=f2; wo[8*b+3]=f3;
            wo[8*b+4]=f4; wo[8*b+5]=f5; wo[8*b+6]=f6; wo[8*b+7]=f7;
        } else if (qp == 15) {
            bI[0]=f0; bI[1]=f1; bI[2]=f2; bI[3]=f3; bI[4]=f4; bI[5]=f5; bI[6]=f6; bI[7]=f7;
        } else if (qp == 16) {
            bG[0]=f0; bG[1]=f1; bG[2]=f2; bG[3]=f3; bG[4]=f4; bG[5]=f5; bG[6]=f6; bG[7]=f7;
        } else if (qp == 17) {
            bO[0]=f0; bO[1]=f1; bO[2]=f2; bO[3]=f3; bO[4]=f4; bO[5]=f5; bO[6]=f6; bO[7]=f7;
        } else {
            const int l = qp - 18;
            wl[l][0]=f0; wl[l][1]=f1; wl[l][2]=f2; wl[l][3]=f3;
            wl[l][4]=f4; wl[l][5]=f5; wl[l][6]=f6; wl[l][7]=f7;
        }
    }
    const float blin = (lane < 7 && wave == 0) ? b_lin[lane] : 0.f;

    float pv0 = 0.f, pv1 = 0.f, pv2 = 1.f, pv3 = 0.f, pv4 = 0.f;

    for (int t = 0; t < NSTEPS; ++t) {
        float a0 = 0.f, a1 = 0.f, a2 = 0.f, a3 = 0.f, a4 = 0.f, a5 = 0.f, a6 = 0.f;
#pragma unroll
        for (int r = 0; r < JPT; ++r) {
            float gi = fmaf(wi[r*5+4], pv4, fmaf(wi[r*5+3], pv3, fmaf(wi[r*5+2], pv2, fmaf(wi[r*5+1], pv1, fmaf(wi[r*5+0], pv0, bI[r])))));
            float gg = fmaf(wg[r*5+4], pv4, fmaf(wg[r*5+3], pv3, fmaf(wg[r*5+2], pv2, fmaf(wg[r*5+1], pv1, fmaf(wg[r*5+0], pv0, bG[r])))));
            float go = fmaf(wo[r*5+4], pv4, fmaf(wo[r*5+3], pv3, fmaf(wo[r*5+2], pv2, fmaf(wo[r*5+1], pv1, fmaf(wo[r*5+0], pv0, bO[r])))));
            float ei = __expf(-gi);
            float eg = __expf(gg + gg);
            float cg = __fdividef(eg - 1.f, (1.f + ei) * (eg + 1.f));   // sig(i)*tanh(g)
            float eo = __expf(-go);
            float ec = __expf(cg + cg);
            float hj = __fdividef(ec - 1.f, (1.f + eo) * (ec + 1.f));   // sig(o)*tanh(c)
            a0 = fmaf(wl[0][r], hj, a0);
            a1 = fmaf(wl[1][r], hj, a1);
            a2 = fmaf(wl[2][r], hj, a2);
            a3 = fmaf(wl[3][r], hj, a3);
            a4 = fmaf(wl[4][r], hj, a4);
            a5 = fmaf(wl[5][r], hj, a5);
            a6 = fmaf(wl[6][r], hj, a6);
        }
#pragma unroll
        for (int m = 1; m < 64; m <<= 1) {
            a0 += __shfl_xor(a0, m, 64);
            a1 += __shfl_xor(a1, m, 64);
            a2 += __shfl_xor(a2, m, 64);
            a3 += __shfl_xor(a3, m, 64);
            a4 += __shfl_xor(a4, m, 64);
            a5 += __shfl_xor(a5, m, 64);
            a6 += __shfl_xor(a6, m, 64);
        }
        if (lane == 0) {
            s_part[wave][0] = a0; s_part[wave][1] = a1; s_part[wave][2] = a2;
            s_part[wave][3] = a3; s_part[wave][4] = a4; s_part[wave][5] = a5;
            s_part[wave][6] = a6;
        }
        __syncthreads();
        if (wave == 0) {
            const int l = lane < 7 ? lane : 0;
            float s = blin;
#pragma unroll
            for (int w = 0; w < 8; ++w) s += s_part[w][l];
            float e2 = __expf(s + s);
            float lg = __fdividef(e2 - 1.f, e2 + 1.f);
            float l0 = __shfl(lg, 0, 64), l1 = __shfl(lg, 1, 64), l2 = __shfl(lg, 2, 64);
            float l3 = __shfl(lg, 3, 64), l4 = __shfl(lg, 4, 64), l5 = __shfl(lg, 5, 64);
            float l6 = __shfl(lg, 6, 64);
            if (lane == 0) {
                float mx = fmaxf(l4, fmaxf(l5, l6));
                float e0 = __expf(l4 - mx), e1 = __expf(l5 - mx), e2b = __expf(l6 - mx);
                float inv = __fdividef(1.f, e0 + e1 + e2b);
                float p0 = e0 * inv, p1 = e1 * inv, p2 = e2b * inv;
                float x0 = l0 + __expf(l1 * 0.5f) * s_noise[2 * t];
                float x1 = l2 + __expf(l3 * 0.5f) * s_noise[2 * t + 1];
                float* row = out + (t + 1) * 5;
                row[0] = x0; row[1] = x1; row[2] = p0; row[3] = p1; row[4] = p2;
                s_prev[0] = x0; s_prev[1] = x1; s_prev[2] = p0; s_prev[3] = p1; s_prev[4] = p2;
                // argmax(new_row[2:]) == 2 (numpy first-index ties) iff p2 strictly beats p0 and p1
                s_prev[5] = (p2 > p0 && p2 > p1) ? 1.f : 0.f;
            }
        }
        __syncthreads();
        pv0 = s_prev[0]; pv1 = s_prev[1]; pv2 = s_prev[2]; pv3 = s_prev[3]; pv4 = s_prev[4];
        if (s_prev[5] != 0.f) break;   // uniform across block; later rows pre-zeroed
    }
}

extern "C" void kernel_launch(void* const* d_in, const int* in_sizes, int n_in,
                              void* d_out, int out_size, void* d_ws, size_t ws_size,
                              hipStream_t stream) {
    const float* W_ih  = (const float*)d_in[0];
    // d_in[1] = W_hh: mathematically dead (h = c = 0 every step) — never read.
    const float* b_ih  = (const float*)d_in[2];
    const float* b_hh  = (const float*)d_in[3];
    const float* W_lin = (const float*)d_in[4];
    const float* b_lin = (const float*)d_in[5];
    const float* noise = (const float*)d_in[6];
    float* out = (float*)d_out;

    hipLaunchKernelGGL(sketch_fused, dim3(NPACK + 1), dim3(NT), 0, stream,
                       W_ih, b_ih, b_hh, W_lin, b_lin, noise, out,
                       (unsigned char*)d_ws);
}